// Round 12
// baseline (123.474 us; speedup 1.0000x reference)
//
#include <hip/hip_runtime.h>
#include <math.h>

#define B_IMG 16
#define HW 409600
#define HW4 102400           // HW/4
#define HW2 204800           // HW/2

// ---- k_geo10 geometry: 200 blocks/img, 2048 elems/block, 4 f2 stages ------
#define GEO_PBI 200
#define GEO_NBLK (B_IMG * GEO_PBI)   // 3200

// ---- cls/collect geometry: 100 blocks/img, 1024 f4/block, no guards -------
#define P_BLK 100
#define TPB 256
#define NBLK2 (B_IMG * P_BLK)        // 1600
#define DICE_SLOTS (NBLK2 + B_IMG)   // 1616

#define SEL_CAP 65536
#define FIX_CAP 65536

// workspace layout (bytes)
#define OFF_GEO    0                 // 3200 doubles (25600)
#define OFF_DICE   25600             // 1616*3 doubles (38784) -> 64384
#define OFF_CNT    64384             // 16*2 u32
#define OFF_STATE  64512             // 16*8 u32
#define OFF_HA     65024             // 16*2048 u32 (131072)
#define OFF_HB     196096            // 16*2048 u32 (131072)
#define OFF_BCNT   327168            // 16 u32
#define OFF_FCNT   327232            // 16 u32
#define ZERO_BYTES (327296 - OFF_CNT)   // 262912
#define ZERO_U4    (ZERO_BYTES / 16)    // 16432
#define OFF_SELB   327296            // 16*65536 u32 (4 MB)
#define OFF_FIXB   4521600           // 16*65536 float2 (8 MB)

typedef float f32x2 __attribute__((ext_vector_type(2)));

union F4 { float4 v; float f[4]; };
union F2 { float2 v; f32x2 n; float f[2]; };

__device__ __forceinline__ f32x2 ntload2(const float* p) {
    return __builtin_nontemporal_load((const f32x2*)p);
}

__device__ __forceinline__ unsigned fkey(float x) {
    unsigned b = __float_as_uint(x);
    return b ^ ((b & 0x80000000u) ? 0xFFFFFFFFu : 0x80000000u);
}
__device__ __forceinline__ float funkey(unsigned k) {
    unsigned b = (k & 0x80000000u) ? (k ^ 0x80000000u) : ~k;
    return __uint_as_float(b);
}

__device__ __forceinline__ double wredd(double v) {
#pragma unroll
    for (int off = 32; off > 0; off >>= 1) v += __shfl_down(v, off);
    return v;
}
__device__ __forceinline__ unsigned wredu(unsigned v) {
#pragma unroll
    for (int off = 32; off > 0; off >>= 1) v += __shfl_down(v, off);
    return v;
}

// n-th largest: find bin and 1-based rank r within that bin. one wave.
__device__ void radix_scan(const unsigned* h, int NB, unsigned n,
                           unsigned& bin_out, unsigned& r_out, bool& tgt) {
    const int lane = threadIdx.x;
    const int seg = NB >> 6;
    const int base = lane * seg;
    unsigned segsum = 0;
    for (int j = 0; j < seg; ++j) segsum += h[base + j];
    unsigned suf = segsum;
#pragma unroll
    for (int off = 1; off < 64; off <<= 1) {
        unsigned v = __shfl_down(suf, off);
        if (lane + off < 64) suf += v;
    }
    unsigned above = suf - segsum;
    tgt = (suf >= n) && (above < n);
    bin_out = 0; r_out = 0;
    if (tgt) {
        unsigned cum = above;
        for (int j = base + seg - 1; j >= base; --j) {
            unsigned cb = cum;
            cum += h[j];
            if (cum >= n) { bin_out = (unsigned)j; r_out = n - cb; break; }
        }
    }
}

// ---------- K0: zero counts/state/hists/bucket-counters ---------------------
__global__ void __launch_bounds__(256)
k_zero(uint4* __restrict__ z) {
    const int i = blockIdx.x * 256 + threadIdx.x;
    if (i < ZERO_U4) z[i] = make_uint4(0u, 0u, 0u, 0u);
}

// ---------- k_cls: counts + packed pass-1 hist (s,g,tm only) ----------------
__global__ void __launch_bounds__(TPB)
k_cls(const float* __restrict__ ypc, const float* __restrict__ ytc,
      const float* __restrict__ tmk,
      unsigned* __restrict__ counts, unsigned* __restrict__ histA,
      unsigned* __restrict__ histB) {
    __shared__ unsigned long long lh[2048];
    const int tid = threadIdx.x;
    const int img = blockIdx.x / P_BLK, blk = blockIdx.x % P_BLK;
    const int cbase = img * HW4 + blk * 1024;
    for (int j = tid; j < 2048; j += TPB) lh[j] = 0ull;
    __syncthreads();
    const float4* sc = (const float4*)ypc;
    const float4* gt = (const float4*)ytc;
    const float4* tm = (const float4*)tmk;
    unsigned pos = 0, neg = 0;
#pragma unroll
    for (int k = 0; k < 4; ++k) {
        const int t = tid + k * TPB;
        F4 s, g, m; s.v = sc[cbase + t]; g.v = gt[cbase + t]; m.v = tm[cbase + t];
#pragma unroll
        for (int j = 0; j < 4; ++j) {
            const float gv = g.f[j], mv = m.f[j];
            pos += (gv > 0.5f && mv > 0.5f) ? 1u : 0u;
            const bool isneg = (gv < 0.5f);
            neg += isneg ? 1u : 0u;
            const unsigned bin = fkey(s.f[j]) >> 21;
            atomicAdd(&lh[bin], 1ull + ((unsigned long long)(isneg ? 1u : 0u) << 32));
        }
    }
    const unsigned pw = wredu(pos), nw = wredu(neg);
    __shared__ unsigned pr[4], nr[4];
    const int lane = tid & 63, w = tid >> 6;
    if (lane == 0) { pr[w] = pw; nr[w] = nw; }
    __syncthreads();
    if (tid == 0) {
        atomicAdd(&counts[img * 2 + 0], pr[0] + pr[1] + pr[2] + pr[3]);
        atomicAdd(&counts[img * 2 + 1], nr[0] + nr[1] + nr[2] + nr[3]);
    }
    for (int j = tid; j < 2048; j += TPB) {
        const unsigned long long v = lh[j];
        const unsigned a = (unsigned)(v & 0xFFFFFFFFull);
        const unsigned b = (unsigned)(v >> 32);
        if (a) atomicAdd(&histA[img * 2048 + j], a);
        if (b) atomicAdd(&histB[img * 2048 + j], b);
    }
}

// ---------- k_geo10: pure 10-stream geo loss, no LDS, f2 2-deep -------------
struct Geo10 {
    F2 d1g, d2g, d3g, d4g, thg, d1p, d2p, d3p, d4p, thp;
};

__device__ __forceinline__ void geo_load(Geo10& r, int idx,
        const float* __restrict__ ytg, const float* __restrict__ ypg, int gb) {
    r.d1g.n = ntload2(ytg + 2 * (gb + 0 * HW2 + idx));
    r.d2g.n = ntload2(ytg + 2 * (gb + 1 * HW2 + idx));
    r.d3g.n = ntload2(ytg + 2 * (gb + 2 * HW2 + idx));
    r.d4g.n = ntload2(ytg + 2 * (gb + 3 * HW2 + idx));
    r.thg.n = ntload2(ytg + 2 * (gb + 4 * HW2 + idx));
    r.d1p.n = ntload2(ypg + 2 * (gb + 0 * HW2 + idx));
    r.d2p.n = ntload2(ypg + 2 * (gb + 1 * HW2 + idx));
    r.d3p.n = ntload2(ypg + 2 * (gb + 2 * HW2 + idx));
    r.d4p.n = ntload2(ypg + 2 * (gb + 3 * HW2 + idx));
    r.thp.n = ntload2(ypg + 2 * (gb + 4 * HW2 + idx));
}

__device__ __forceinline__ void geo_compute(const Geo10& r, const F2& g, const F2& m,
                                            float& geo_f) {
#pragma unroll
    for (int j = 0; j < 2; ++j) {
        const float gv = g.f[j], mv = m.f[j];
        const float ag = (r.d1g.f[j] + r.d3g.f[j]) * (r.d2g.f[j] + r.d4g.f[j]);
        const float ap = (r.d1p.f[j] + r.d3p.f[j]) * (r.d2p.f[j] + r.d4p.f[j]);
        const float wu = fminf(r.d2g.f[j], r.d2p.f[j]) + fminf(r.d4g.f[j], r.d4p.f[j]);
        const float hu = fminf(r.d1g.f[j], r.d1p.f[j]) + fminf(r.d3g.f[j], r.d3p.f[j]);
        const float ai = wu * hu;
        const float au = ag + ap - ai;
        const float la = __logf(__fdividef(au + 1.0f, ai + 1.0f));
        const float lt = 1.0f - __cosf(r.thp.f[j] - r.thg.f[j]);
        geo_f += (la + 20.0f * lt) * gv * mv;
    }
}

__global__ void k_geo10(const float* __restrict__ ytc, const float* __restrict__ tmk,
                        const float* __restrict__ ytg, const float* __restrict__ ypg,
                        double* __restrict__ geo_part) {
    const int tid = threadIdx.x;
    const int img = blockIdx.x / GEO_PBI, blkin = blockIdx.x % GEO_PBI;
    const int cb = img * HW2;
    const int gb = img * 5 * HW2;
    const int base = blkin * 1024 + tid;

    float geo_f = 0.0f;
    Geo10 A, B;
    F2 gA, mA, gB, mB, gA2, mA2, gB2, mB2;

    geo_load(A, base + 0 * 256, ytg, ypg, gb);
    gA.v = ((const float2*)ytc)[cb + base + 0 * 256];
    mA.v = ((const float2*)tmk)[cb + base + 0 * 256];
    geo_load(B, base + 1 * 256, ytg, ypg, gb);
    gB.v = ((const float2*)ytc)[cb + base + 1 * 256];
    mB.v = ((const float2*)tmk)[cb + base + 1 * 256];
    __builtin_amdgcn_sched_barrier(0);
    geo_compute(A, gA, mA, geo_f);
    geo_load(A, base + 2 * 256, ytg, ypg, gb);
    gA2.v = ((const float2*)ytc)[cb + base + 2 * 256];
    mA2.v = ((const float2*)tmk)[cb + base + 2 * 256];
    __builtin_amdgcn_sched_barrier(0);
    geo_compute(B, gB, mB, geo_f);
    geo_load(B, base + 3 * 256, ytg, ypg, gb);
    gB2.v = ((const float2*)ytc)[cb + base + 3 * 256];
    mB2.v = ((const float2*)tmk)[cb + base + 3 * 256];
    __builtin_amdgcn_sched_barrier(0);
    geo_compute(A, gA2, mA2, geo_f);
    geo_compute(B, gB2, mB2, geo_f);

    const double gw = wredd((double)geo_f);
    __shared__ double gred[4];
    const int lane = tid & 63, w = tid >> 6;
    if (lane == 0) gred[w] = gw;
    __syncthreads();
    if (tid == 0)
        geo_part[blockIdx.x] = gred[0] + gred[1] + gred[2] + gred[3];
}

// ---------- scan1: decide branch, pick 11-bit bin + rank --------------------
__global__ void k_scan1(const unsigned* __restrict__ counts,
                        const unsigned* __restrict__ histA,
                        const unsigned* __restrict__ histB,
                        unsigned* __restrict__ state) {
    const int img = blockIdx.x, lane = threadIdx.x;
    const unsigned pos = counts[img * 2 + 0], neg = counts[img * 2 + 1];
    unsigned branch, n = 1;
    if (pos == 0) {
        branch = 0;
        n = neg / 2; if (n < 1) n = 1;
    } else {
        const unsigned n3 = min(pos * 3u, neg);
        if (n3 == 0) branch = 1;
        else { branch = 2; n = n3; }
    }
    if (lane == 0) state[img * 8 + 0] = branch;
    if (branch == 1) return;
    __shared__ unsigned h[2048];
    const unsigned* g = (branch == 0 ? histA : histB) + img * 2048;
    for (int j = lane; j < 2048; j += 64) h[j] = g[j];
    __syncthreads();
    unsigned bin, r; bool tgt;
    radix_scan(h, 2048, n, bin, r, tgt);
    if (tgt) { state[img * 8 + 1] = bin; state[img * 8 + 2] = r; }
}

// ---------- collect2: in-bin keys + dice for definite pixels ----------------
__global__ void __launch_bounds__(TPB)
k_collect2(const float* __restrict__ ypc, const float* __restrict__ ytc,
           const float* __restrict__ tmk, const unsigned* __restrict__ state,
           unsigned* __restrict__ bcnt, unsigned* __restrict__ bucket,
           unsigned* __restrict__ fcnt, float2* __restrict__ fixb,
           double* __restrict__ dice_part) {
    const int img = blockIdx.x / P_BLK, blk = blockIdx.x % P_BLK;
    const unsigned branch = state[img * 8 + 0];
    const unsigned bin = state[img * 8 + 1];
    const int cbase = img * HW4 + blk * 1024;
    const int lane = threadIdx.x & 63;
    const unsigned long long lmlt = (1ull << lane) - 1ull;
    const float4* sc = (const float4*)ypc;
    const float4* gt = (const float4*)ytc;
    const float4* tm = (const float4*)tmk;
    unsigned* bk = bucket + (size_t)img * SEL_CAP;
    float2*   fb = fixb + (size_t)img * FIX_CAP;

    float di = 0.0f, dg = 0.0f, dp = 0.0f;
#pragma unroll
    for (int k = 0; k < 4; ++k) {
        const int t = threadIdx.x + k * TPB;
        F4 s, g, m; s.v = sc[cbase + t]; g.v = gt[cbase + t]; m.v = tm[cbase + t];
        if (branch == 1) {
#pragma unroll
            for (int j = 0; j < 4; ++j) {
                const float sv = s.f[j], gv = g.f[j], mv = m.f[j];
                di += gv * sv * mv; dg += gv * mv; dp += sv * mv;
            }
        } else {
#pragma unroll
            for (int j = 0; j < 4; ++j) {
                const float sv = s.f[j], gv = g.f[j], mv = m.f[j];
                const unsigned key = fkey(sv);
                const unsigned kb = key >> 21;
                const bool cand = (branch == 0) || (gv < 0.5f);
                const bool selp = cand && (kb == bin);
                const unsigned long long msk = __ballot(selp);
                if (msk) {
                    const int leader = __ffsll((long long)msk) - 1;
                    unsigned b0 = 0;
                    if (lane == leader)
                        b0 = atomicAdd(&bcnt[img], (unsigned)__popcll(msk));
                    b0 = (unsigned)__shfl((int)b0, leader);
                    const unsigned idx = b0 + (unsigned)__popcll(msk & lmlt);
                    if (selp && idx < SEL_CAP) bk[idx] = key;
                }
                bool unc; float mm;
                if (branch == 0) {
                    unc = (kb == bin);
                    mm = (kb > bin) ? 1.0f : 0.0f;
                } else {
                    if (gv > 0.5f)       { unc = false; mm = (mv > 0.5f) ? 1.0f : 0.0f; }
                    else if (mv <= 0.5f) { unc = false; mm = 0.0f; }
                    else                 { unc = (kb == bin); mm = (kb > bin) ? 1.0f : 0.0f; }
                }
                if (!unc) { di += gv * sv * mm; dg += gv * mm; dp += sv * mm; }
                const unsigned long long msk2 = __ballot(unc);
                if (msk2) {
                    const int leader = __ffsll((long long)msk2) - 1;
                    unsigned b0 = 0;
                    if (lane == leader)
                        b0 = atomicAdd(&fcnt[img], (unsigned)__popcll(msk2));
                    b0 = (unsigned)__shfl((int)b0, leader);
                    const unsigned idx = b0 + (unsigned)__popcll(msk2 & lmlt);
                    if (unc && idx < FIX_CAP) fb[idx] = make_float2(sv, gv);
                }
            }
        }
    }
    const double a = wredd((double)di), b = wredd((double)dg), c = wredd((double)dp);
    __shared__ double r[4][3];
    const int wid = threadIdx.x >> 6;
    if (lane == 0) { r[wid][0] = a; r[wid][1] = b; r[wid][2] = c; }
    __syncthreads();
    if (threadIdx.x == 0) {
        dice_part[blockIdx.x * 3 + 0] = r[0][0] + r[1][0] + r[2][0] + r[3][0];
        dice_part[blockIdx.x * 3 + 1] = r[0][1] + r[1][1] + r[2][1] + r[3][1];
        dice_part[blockIdx.x * 3 + 2] = r[0][2] + r[1][2] + r[2][2] + r[3][2];
    }
}

// ---------- select: exact n-th value within the bucket ----------------------
__global__ void k_select(unsigned* __restrict__ state,
                         const unsigned* __restrict__ bcnt,
                         const unsigned* __restrict__ bucket) {
    const int img = blockIdx.x, lane = threadIdx.x;
    const unsigned branch = state[img * 8 + 0];
    if (branch == 1) return;
    const unsigned bin = state[img * 8 + 1];
    const unsigned r = state[img * 8 + 2];
    const unsigned cnt = min(bcnt[img], (unsigned)SEL_CAP);
    const unsigned* bk = bucket + (size_t)img * SEL_CAP;
    __shared__ unsigned h[2048];
    __shared__ unsigned sh_mid, sh_r2;
    for (int j = lane; j < 2048; j += 64) h[j] = 0;
    __syncthreads();
    for (unsigned i = lane; i < cnt; i += 64)
        atomicAdd(&h[(bk[i] >> 10) & 2047u], 1u);
    __syncthreads();
    unsigned mid, r2; bool tgt;
    radix_scan(h, 2048, r, mid, r2, tgt);
    if (tgt) { sh_mid = mid; sh_r2 = r2; }
    __syncthreads();
    mid = sh_mid; r2 = sh_r2;
    for (int j = lane; j < 1024; j += 64) h[j] = 0;
    __syncthreads();
    for (unsigned i = lane; i < cnt; i += 64) {
        const unsigned k = bk[i];
        if (((k >> 10) & 2047u) == mid) atomicAdd(&h[k & 1023u], 1u);
    }
    __syncthreads();
    unsigned low, r3;
    radix_scan(h, 1024, r2, low, r3, tgt);
    if (tgt)
        state[img * 8 + 4] = __float_as_uint(funkey((bin << 21) | (mid << 10) | low));
}

// ---------- fix: dice contribution of the in-bin pixels ---------------------
__global__ void __launch_bounds__(256)
k_fix(const unsigned* __restrict__ state, const unsigned* __restrict__ fcnt,
      const float2* __restrict__ fixb, double* __restrict__ dice_part) {
    const int img = blockIdx.x;
    const unsigned branch = state[img * 8 + 0];
    const float thr = __uint_as_float(state[img * 8 + 4]);
    double di = 0.0, dg = 0.0, dp = 0.0;
    if (branch != 1) {
        const unsigned cnt = min(fcnt[img], (unsigned)FIX_CAP);
        const float2* fb = fixb + (size_t)img * FIX_CAP;
        for (unsigned i = threadIdx.x; i < cnt; i += 256) {
            const float sv = fb[i].x, gv = fb[i].y;
            if (sv >= thr) { di += (double)(gv * sv); dg += (double)gv; dp += (double)sv; }
        }
    }
    const double a = wredd(di), b = wredd(dg), c = wredd(dp);
    __shared__ double r[4][3];
    const int lane = threadIdx.x & 63, wid = threadIdx.x >> 6;
    if (lane == 0) { r[wid][0] = a; r[wid][1] = b; r[wid][2] = c; }
    __syncthreads();
    if (threadIdx.x == 0) {
        const int slot = NBLK2 + img;
        dice_part[slot * 3 + 0] = r[0][0] + r[1][0] + r[2][0] + r[3][0];
        dice_part[slot * 3 + 1] = r[0][1] + r[1][1] + r[2][1] + r[3][1];
        dice_part[slot * 3 + 2] = r[0][2] + r[1][2] + r[2][2] + r[3][2];
    }
}

// ---------- combine ---------------------------------------------------------
__global__ void __launch_bounds__(256)
k_out(const double* __restrict__ geo_part, const double* __restrict__ dice_part,
      float* __restrict__ out) {
    double geo = 0.0, di = 0.0, dg = 0.0, dp = 0.0;
    for (int i = threadIdx.x; i < GEO_NBLK; i += 256) {
        geo += geo_part[i];
        if (i < DICE_SLOTS) {
            di += dice_part[i * 3 + 0];
            dg += dice_part[i * 3 + 1];
            dp += dice_part[i * 3 + 2];
        }
    }
    geo = wredd(geo); di = wredd(di); dg = wredd(dg); dp = wredd(dp);
    __shared__ double r[4][4];
    const int lane = threadIdx.x & 63, wid = threadIdx.x >> 6;
    if (lane == 0) { r[wid][0] = geo; r[wid][1] = di; r[wid][2] = dg; r[wid][3] = dp; }
    __syncthreads();
    if (threadIdx.x == 0) {
        geo = r[0][0] + r[1][0] + r[2][0] + r[3][0];
        di  = r[0][1] + r[1][1] + r[2][1] + r[3][1];
        dg  = r[0][2] + r[1][2] + r[2][2] + r[3][2];
        dp  = r[0][3] + r[1][3] + r[2][3] + r[3][3];
        const double mean = geo / (double)((double)B_IMG * (double)HW);
        const double uni = dg + dp + 1e-05;
        const double loss = mean + 0.01 * (1.0 - 2.0 * di / uni);
        out[0] = (float)loss;
    }
}

extern "C" void kernel_launch(void* const* d_in, const int* in_sizes, int n_in,
                              void* d_out, int out_size, void* d_ws, size_t ws_size,
                              hipStream_t stream) {
    const float* ytc = (const float*)d_in[0];  // y_true_cls  (gt)
    const float* ypc = (const float*)d_in[1];  // y_pred_cls  (score)
    const float* ytg = (const float*)d_in[2];  // y_true_geo
    const float* ypg = (const float*)d_in[3];  // y_pred_geo
    const float* tmk = (const float*)d_in[4];  // training_mask

    char* ws = (char*)d_ws;
    double*   geo_part  = (double*)(ws + OFF_GEO);
    double*   dice_part = (double*)(ws + OFF_DICE);
    unsigned* counts    = (unsigned*)(ws + OFF_CNT);
    unsigned* state     = (unsigned*)(ws + OFF_STATE);
    unsigned* histA     = (unsigned*)(ws + OFF_HA);
    unsigned* histB     = (unsigned*)(ws + OFF_HB);
    unsigned* bcnt      = (unsigned*)(ws + OFF_BCNT);
    unsigned* fcnt      = (unsigned*)(ws + OFF_FCNT);
    unsigned* bucket    = (unsigned*)(ws + OFF_SELB);
    float2*   fixb      = (float2*)(ws + OFF_FIXB);

    k_zero<<<(ZERO_U4 + 255) / 256, 256, 0, stream>>>((uint4*)(ws + OFF_CNT));
    k_cls<<<NBLK2, TPB, 0, stream>>>(ypc, ytc, tmk, counts, histA, histB);
    k_scan1<<<B_IMG, 64, 0, stream>>>(counts, histA, histB, state);
    k_collect2<<<NBLK2, TPB, 0, stream>>>(ypc, ytc, tmk, state,
                                          bcnt, bucket, fcnt, fixb, dice_part);
    k_select<<<B_IMG, 64, 0, stream>>>(state, bcnt, bucket);
    k_fix<<<B_IMG, 256, 0, stream>>>(state, fcnt, fixb, dice_part);
    k_geo10<<<GEO_NBLK, 256, 0, stream>>>(ytc, tmk, ytg, ypg, geo_part);
    k_out<<<1, 256, 0, stream>>>(geo_part, dice_part, (float*)d_out);
}

// Round 13
// 107.822 us; speedup vs baseline: 1.1452x; 1.1452x over previous
//
#include <hip/hip_runtime.h>
#include <math.h>

#define B_IMG 16
#define HW 409600
#define HW4 102400           // HW/4
#define HW2 204800           // HW/2

// ---- k_geo geometry: 100 blocks/img, 1024 float4/block, 4 stages ----------
#define GEO_PBI 100
#define GEO_NBLK (B_IMG * GEO_PBI)   // 1600

// ---- collect geometry: 100 blocks/img, 1024 f4/block, no guards -----------
#define P_BLK 100
#define TPB 256
#define NBLK2 (B_IMG * P_BLK)        // 1600
#define DICE_SLOTS (NBLK2 + B_IMG)   // 1616

#define SEL_CAP 65536
#define FIX_CAP 65536

// workspace layout (bytes)
#define OFF_GEO    0                 // 1600 doubles (12800)
#define OFF_DICE   12800             // 1616*3 doubles (38784) -> 51584
#define OFF_CNT    51584             // 16*2 u32
#define OFF_STATE  51712             // 16*8 u32
#define OFF_HA     52224             // 16*2048 u32 (131072)
#define OFF_HB     183296            // 16*2048 u32 (131072)
#define OFF_BCNT   314368            // 16 u32
#define OFF_FCNT   314432            // 16 u32
#define ZERO_BYTES (314496 - OFF_CNT)   // 262912
#define ZERO_U4    (ZERO_BYTES / 16)    // 16432
#define OFF_SELB   314496            // 16*65536 u32 (4 MB)
#define OFF_FIXB   4508800           // 16*65536 float2 (8 MB)

typedef float f32x4 __attribute__((ext_vector_type(4)));

union F4 { float4 v; f32x4 n; float f[4]; };

__device__ __forceinline__ f32x4 ntload4(const float* p) {
    return __builtin_nontemporal_load((const f32x4*)p);
}

__device__ __forceinline__ unsigned fkey(float x) {
    unsigned b = __float_as_uint(x);
    return b ^ ((b & 0x80000000u) ? 0xFFFFFFFFu : 0x80000000u);
}
__device__ __forceinline__ float funkey(unsigned k) {
    unsigned b = (k & 0x80000000u) ? (k ^ 0x80000000u) : ~k;
    return __uint_as_float(b);
}

__device__ __forceinline__ double wredd(double v) {
#pragma unroll
    for (int off = 32; off > 0; off >>= 1) v += __shfl_down(v, off);
    return v;
}
__device__ __forceinline__ unsigned wredu(unsigned v) {
#pragma unroll
    for (int off = 32; off > 0; off >>= 1) v += __shfl_down(v, off);
    return v;
}

// n-th largest: find bin and 1-based rank r within that bin. one wave.
__device__ void radix_scan(const unsigned* h, int NB, unsigned n,
                           unsigned& bin_out, unsigned& r_out, bool& tgt) {
    const int lane = threadIdx.x;
    const int seg = NB >> 6;
    const int base = lane * seg;
    unsigned segsum = 0;
    for (int j = 0; j < seg; ++j) segsum += h[base + j];
    unsigned suf = segsum;
#pragma unroll
    for (int off = 1; off < 64; off <<= 1) {
        unsigned v = __shfl_down(suf, off);
        if (lane + off < 64) suf += v;
    }
    unsigned above = suf - segsum;
    tgt = (suf >= n) && (above < n);
    bin_out = 0; r_out = 0;
    if (tgt) {
        unsigned cum = above;
        for (int j = base + seg - 1; j >= base; --j) {
            unsigned cb = cum;
            cum += h[j];
            if (cum >= n) { bin_out = (unsigned)j; r_out = n - cb; break; }
        }
    }
}

// ---------- K0: zero counts/state/hists/bucket-counters ---------------------
__global__ void __launch_bounds__(256)
k_zero(uint4* __restrict__ z) {
    const int i = blockIdx.x * 256 + threadIdx.x;
    if (i < ZERO_U4) z[i] = make_uint4(0u, 0u, 0u, 0u);
}

// ---------- K1: geo loss + counts + packed pass-1 hist, f4 1-deep -----------
struct GeoF4 {
    F4 s, g, m, d1g, d2g, d3g, d4g, thg, d1p, d2p, d3p, d4p, thp;
};

__device__ __forceinline__ void geo_load(GeoF4& r, int idx,
        const float* __restrict__ ypc, const float* __restrict__ ytc,
        const float* __restrict__ tmk, const float* __restrict__ ytg,
        const float* __restrict__ ypg, int cb, int gb) {
    r.s.v   = ((const float4*)ypc)[cb + idx];
    r.g.v   = ((const float4*)ytc)[cb + idx];
    r.m.v   = ((const float4*)tmk)[cb + idx];
    r.d1g.n = ntload4(ytg + 4 * (gb + 0 * HW4 + idx));
    r.d2g.n = ntload4(ytg + 4 * (gb + 1 * HW4 + idx));
    r.d3g.n = ntload4(ytg + 4 * (gb + 2 * HW4 + idx));
    r.d4g.n = ntload4(ytg + 4 * (gb + 3 * HW4 + idx));
    r.thg.n = ntload4(ytg + 4 * (gb + 4 * HW4 + idx));
    r.d1p.n = ntload4(ypg + 4 * (gb + 0 * HW4 + idx));
    r.d2p.n = ntload4(ypg + 4 * (gb + 1 * HW4 + idx));
    r.d3p.n = ntload4(ypg + 4 * (gb + 2 * HW4 + idx));
    r.d4p.n = ntload4(ypg + 4 * (gb + 3 * HW4 + idx));
    r.thp.n = ntload4(ypg + 4 * (gb + 4 * HW4 + idx));
}

__device__ __forceinline__ void geo_compute(const GeoF4& r, float& geo_f,
                                            unsigned& pos, unsigned& neg,
                                            unsigned long long* h) {
#pragma unroll
    for (int j = 0; j < 4; ++j) {
        const float gv = r.g.f[j], mv = r.m.f[j];
        pos += (gv > 0.5f && mv > 0.5f) ? 1u : 0u;
        const bool isneg = (gv < 0.5f);
        neg += isneg ? 1u : 0u;
        const unsigned bin = fkey(r.s.f[j]) >> 21;
        atomicAdd(&h[bin], 1ull + ((unsigned long long)(isneg ? 1u : 0u) << 32));
        const float ag = (r.d1g.f[j] + r.d3g.f[j]) * (r.d2g.f[j] + r.d4g.f[j]);
        const float ap = (r.d1p.f[j] + r.d3p.f[j]) * (r.d2p.f[j] + r.d4p.f[j]);
        const float wu = fminf(r.d2g.f[j], r.d2p.f[j]) + fminf(r.d4g.f[j], r.d4p.f[j]);
        const float hu = fminf(r.d1g.f[j], r.d1p.f[j]) + fminf(r.d3g.f[j], r.d3p.f[j]);
        const float ai = wu * hu;
        const float au = ag + ap - ai;
        const float la = __logf(__fdividef(au + 1.0f, ai + 1.0f));
        const float lt = 1.0f - __cosf(r.thp.f[j] - r.thg.f[j]);
        geo_f += (la + 20.0f * lt) * gv * mv;
    }
}

__global__ void __launch_bounds__(256)
k_geo(const float* __restrict__ ypc, const float* __restrict__ ytc,
      const float* __restrict__ ytg, const float* __restrict__ ypg,
      const float* __restrict__ tmk,
      unsigned* __restrict__ counts, unsigned* __restrict__ histA,
      unsigned* __restrict__ histB, double* __restrict__ geo_part) {
    __shared__ unsigned long long lh[2048];
    const int tid = threadIdx.x;
    const int img = blockIdx.x / GEO_PBI, blkin = blockIdx.x % GEO_PBI;
    const int cb = img * HW4;
    const int gb = img * 5 * HW4;
    const int base = blkin * 1024 + tid;

    for (int j = tid; j < 2048; j += 256) lh[j] = 0ull;
    __syncthreads();

    float geo_f = 0.0f;
    unsigned pos = 0, neg = 0;

    GeoF4 A;
    // 1-deep: all 13 f4 loads issued (one shared voffset), barrier, compute.
    geo_load(A, base + 0 * 256, ypc, ytc, tmk, ytg, ypg, cb, gb);
    __builtin_amdgcn_sched_barrier(0);
    geo_compute(A, geo_f, pos, neg, lh);
    __builtin_amdgcn_sched_barrier(0);
    geo_load(A, base + 1 * 256, ypc, ytc, tmk, ytg, ypg, cb, gb);
    __builtin_amdgcn_sched_barrier(0);
    geo_compute(A, geo_f, pos, neg, lh);
    __builtin_amdgcn_sched_barrier(0);
    geo_load(A, base + 2 * 256, ypc, ytc, tmk, ytg, ypg, cb, gb);
    __builtin_amdgcn_sched_barrier(0);
    geo_compute(A, geo_f, pos, neg, lh);
    __builtin_amdgcn_sched_barrier(0);
    geo_load(A, base + 3 * 256, ypc, ytc, tmk, ytg, ypg, cb, gb);
    __builtin_amdgcn_sched_barrier(0);
    geo_compute(A, geo_f, pos, neg, lh);

    const double gw = wredd((double)geo_f);
    const unsigned pw = wredu(pos), nw = wredu(neg);
    __shared__ double gred[4];
    __shared__ unsigned pr[4], nr[4];
    const int lane = tid & 63, w = tid >> 6;
    if (lane == 0) { gred[w] = gw; pr[w] = pw; nr[w] = nw; }
    __syncthreads();
    if (tid == 0) {
        geo_part[blockIdx.x] = gred[0] + gred[1] + gred[2] + gred[3];
        atomicAdd(&counts[img * 2 + 0], pr[0] + pr[1] + pr[2] + pr[3]);
        atomicAdd(&counts[img * 2 + 1], nr[0] + nr[1] + nr[2] + nr[3]);
    }
    for (int j = tid; j < 2048; j += 256) {
        const unsigned long long v = lh[j];
        const unsigned a = (unsigned)(v & 0xFFFFFFFFull);
        const unsigned b = (unsigned)(v >> 32);
        if (a) atomicAdd(&histA[img * 2048 + j], a);
        if (b) atomicAdd(&histB[img * 2048 + j], b);
    }
}

// ---------- scan1: decide branch, pick 11-bit bin + rank --------------------
__global__ void k_scan1(const unsigned* __restrict__ counts,
                        const unsigned* __restrict__ histA,
                        const unsigned* __restrict__ histB,
                        unsigned* __restrict__ state) {
    const int img = blockIdx.x, lane = threadIdx.x;
    const unsigned pos = counts[img * 2 + 0], neg = counts[img * 2 + 1];
    unsigned branch, n = 1;
    if (pos == 0) {
        branch = 0;
        n = neg / 2; if (n < 1) n = 1;
    } else {
        const unsigned n3 = min(pos * 3u, neg);
        if (n3 == 0) branch = 1;
        else { branch = 2; n = n3; }
    }
    if (lane == 0) state[img * 8 + 0] = branch;
    if (branch == 1) return;
    __shared__ unsigned h[2048];
    const unsigned* g = (branch == 0 ? histA : histB) + img * 2048;
    for (int j = lane; j < 2048; j += 64) h[j] = g[j];
    __syncthreads();
    unsigned bin, r; bool tgt;
    radix_scan(h, 2048, n, bin, r, tgt);
    if (tgt) { state[img * 8 + 1] = bin; state[img * 8 + 2] = r; }
}

// ---------- collect2: in-bin keys + dice for definite pixels ----------------
__global__ void __launch_bounds__(TPB)
k_collect2(const float* __restrict__ ypc, const float* __restrict__ ytc,
           const float* __restrict__ tmk, const unsigned* __restrict__ state,
           unsigned* __restrict__ bcnt, unsigned* __restrict__ bucket,
           unsigned* __restrict__ fcnt, float2* __restrict__ fixb,
           double* __restrict__ dice_part) {
    const int img = blockIdx.x / P_BLK, blk = blockIdx.x % P_BLK;
    const unsigned branch = state[img * 8 + 0];
    const unsigned bin = state[img * 8 + 1];
    const int cbase = img * HW4 + blk * 1024;
    const int lane = threadIdx.x & 63;
    const unsigned long long lmlt = (1ull << lane) - 1ull;
    const float4* sc = (const float4*)ypc;
    const float4* gt = (const float4*)ytc;
    const float4* tm = (const float4*)tmk;
    unsigned* bk = bucket + (size_t)img * SEL_CAP;
    float2*   fb = fixb + (size_t)img * FIX_CAP;

    float di = 0.0f, dg = 0.0f, dp = 0.0f;
#pragma unroll
    for (int k = 0; k < 4; ++k) {
        const int t = threadIdx.x + k * TPB;
        F4 s, g, m; s.v = sc[cbase + t]; g.v = gt[cbase + t]; m.v = tm[cbase + t];
        if (branch == 1) {
#pragma unroll
            for (int j = 0; j < 4; ++j) {
                const float sv = s.f[j], gv = g.f[j], mv = m.f[j];
                di += gv * sv * mv; dg += gv * mv; dp += sv * mv;
            }
        } else {
#pragma unroll
            for (int j = 0; j < 4; ++j) {
                const float sv = s.f[j], gv = g.f[j], mv = m.f[j];
                const unsigned key = fkey(sv);
                const unsigned kb = key >> 21;
                const bool cand = (branch == 0) || (gv < 0.5f);
                const bool selp = cand && (kb == bin);
                const unsigned long long msk = __ballot(selp);
                if (msk) {
                    const int leader = __ffsll((long long)msk) - 1;
                    unsigned b0 = 0;
                    if (lane == leader)
                        b0 = atomicAdd(&bcnt[img], (unsigned)__popcll(msk));
                    b0 = (unsigned)__shfl((int)b0, leader);
                    const unsigned idx = b0 + (unsigned)__popcll(msk & lmlt);
                    if (selp && idx < SEL_CAP) bk[idx] = key;
                }
                bool unc; float mm;
                if (branch == 0) {
                    unc = (kb == bin);
                    mm = (kb > bin) ? 1.0f : 0.0f;
                } else {
                    if (gv > 0.5f)       { unc = false; mm = (mv > 0.5f) ? 1.0f : 0.0f; }
                    else if (mv <= 0.5f) { unc = false; mm = 0.0f; }
                    else                 { unc = (kb == bin); mm = (kb > bin) ? 1.0f : 0.0f; }
                }
                if (!unc) { di += gv * sv * mm; dg += gv * mm; dp += sv * mm; }
                const unsigned long long msk2 = __ballot(unc);
                if (msk2) {
                    const int leader = __ffsll((long long)msk2) - 1;
                    unsigned b0 = 0;
                    if (lane == leader)
                        b0 = atomicAdd(&fcnt[img], (unsigned)__popcll(msk2));
                    b0 = (unsigned)__shfl((int)b0, leader);
                    const unsigned idx = b0 + (unsigned)__popcll(msk2 & lmlt);
                    if (unc && idx < FIX_CAP) fb[idx] = make_float2(sv, gv);
                }
            }
        }
    }
    const double a = wredd((double)di), b = wredd((double)dg), c = wredd((double)dp);
    __shared__ double r[4][3];
    const int wid = threadIdx.x >> 6;
    if (lane == 0) { r[wid][0] = a; r[wid][1] = b; r[wid][2] = c; }
    __syncthreads();
    if (threadIdx.x == 0) {
        dice_part[blockIdx.x * 3 + 0] = r[0][0] + r[1][0] + r[2][0] + r[3][0];
        dice_part[blockIdx.x * 3 + 1] = r[0][1] + r[1][1] + r[2][1] + r[3][1];
        dice_part[blockIdx.x * 3 + 2] = r[0][2] + r[1][2] + r[2][2] + r[3][2];
    }
}

// ---------- select: exact n-th value within the bucket ----------------------
__global__ void k_select(unsigned* __restrict__ state,
                         const unsigned* __restrict__ bcnt,
                         const unsigned* __restrict__ bucket) {
    const int img = blockIdx.x, lane = threadIdx.x;
    const unsigned branch = state[img * 8 + 0];
    if (branch == 1) return;
    const unsigned bin = state[img * 8 + 1];
    const unsigned r = state[img * 8 + 2];
    const unsigned cnt = min(bcnt[img], (unsigned)SEL_CAP);
    const unsigned* bk = bucket + (size_t)img * SEL_CAP;
    __shared__ unsigned h[2048];
    __shared__ unsigned sh_mid, sh_r2;
    for (int j = lane; j < 2048; j += 64) h[j] = 0;
    __syncthreads();
    for (unsigned i = lane; i < cnt; i += 64)
        atomicAdd(&h[(bk[i] >> 10) & 2047u], 1u);
    __syncthreads();
    unsigned mid, r2; bool tgt;
    radix_scan(h, 2048, r, mid, r2, tgt);
    if (tgt) { sh_mid = mid; sh_r2 = r2; }
    __syncthreads();
    mid = sh_mid; r2 = sh_r2;
    for (int j = lane; j < 1024; j += 64) h[j] = 0;
    __syncthreads();
    for (unsigned i = lane; i < cnt; i += 64) {
        const unsigned k = bk[i];
        if (((k >> 10) & 2047u) == mid) atomicAdd(&h[k & 1023u], 1u);
    }
    __syncthreads();
    unsigned low, r3;
    radix_scan(h, 1024, r2, low, r3, tgt);
    if (tgt)
        state[img * 8 + 4] = __float_as_uint(funkey((bin << 21) | (mid << 10) | low));
}

// ---------- fix: dice contribution of the in-bin pixels ---------------------
__global__ void __launch_bounds__(256)
k_fix(const unsigned* __restrict__ state, const unsigned* __restrict__ fcnt,
      const float2* __restrict__ fixb, double* __restrict__ dice_part) {
    const int img = blockIdx.x;
    const unsigned branch = state[img * 8 + 0];
    const float thr = __uint_as_float(state[img * 8 + 4]);
    double di = 0.0, dg = 0.0, dp = 0.0;
    if (branch != 1) {
        const unsigned cnt = min(fcnt[img], (unsigned)FIX_CAP);
        const float2* fb = fixb + (size_t)img * FIX_CAP;
        for (unsigned i = threadIdx.x; i < cnt; i += 256) {
            const float sv = fb[i].x, gv = fb[i].y;
            if (sv >= thr) { di += (double)(gv * sv); dg += (double)gv; dp += (double)sv; }
        }
    }
    const double a = wredd(di), b = wredd(dg), c = wredd(dp);
    __shared__ double r[4][3];
    const int lane = threadIdx.x & 63, wid = threadIdx.x >> 6;
    if (lane == 0) { r[wid][0] = a; r[wid][1] = b; r[wid][2] = c; }
    __syncthreads();
    if (threadIdx.x == 0) {
        const int slot = NBLK2 + img;
        dice_part[slot * 3 + 0] = r[0][0] + r[1][0] + r[2][0] + r[3][0];
        dice_part[slot * 3 + 1] = r[0][1] + r[1][1] + r[2][1] + r[3][1];
        dice_part[slot * 3 + 2] = r[0][2] + r[1][2] + r[2][2] + r[3][2];
    }
}

// ---------- combine ---------------------------------------------------------
__global__ void __launch_bounds__(256)
k_out(const double* __restrict__ geo_part, const double* __restrict__ dice_part,
      float* __restrict__ out) {
    double geo = 0.0, di = 0.0, dg = 0.0, dp = 0.0;
    for (int i = threadIdx.x; i < DICE_SLOTS; i += 256) {
        if (i < GEO_NBLK) geo += geo_part[i];
        di += dice_part[i * 3 + 0];
        dg += dice_part[i * 3 + 1];
        dp += dice_part[i * 3 + 2];
    }
    geo = wredd(geo); di = wredd(di); dg = wredd(dg); dp = wredd(dp);
    __shared__ double r[4][4];
    const int lane = threadIdx.x & 63, wid = threadIdx.x >> 6;
    if (lane == 0) { r[wid][0] = geo; r[wid][1] = di; r[wid][2] = dg; r[wid][3] = dp; }
    __syncthreads();
    if (threadIdx.x == 0) {
        geo = r[0][0] + r[1][0] + r[2][0] + r[3][0];
        di  = r[0][1] + r[1][1] + r[2][1] + r[3][1];
        dg  = r[0][2] + r[1][2] + r[2][2] + r[3][2];
        dp  = r[0][3] + r[1][3] + r[2][3] + r[3][3];
        const double mean = geo / (double)((double)B_IMG * (double)HW);
        const double uni = dg + dp + 1e-05;
        const double loss = mean + 0.01 * (1.0 - 2.0 * di / uni);
        out[0] = (float)loss;
    }
}

extern "C" void kernel_launch(void* const* d_in, const int* in_sizes, int n_in,
                              void* d_out, int out_size, void* d_ws, size_t ws_size,
                              hipStream_t stream) {
    const float* ytc = (const float*)d_in[0];  // y_true_cls  (gt)
    const float* ypc = (const float*)d_in[1];  // y_pred_cls  (score)
    const float* ytg = (const float*)d_in[2];  // y_true_geo
    const float* ypg = (const float*)d_in[3];  // y_pred_geo
    const float* tmk = (const float*)d_in[4];  // training_mask

    char* ws = (char*)d_ws;
    double*   geo_part  = (double*)(ws + OFF_GEO);
    double*   dice_part = (double*)(ws + OFF_DICE);
    unsigned* counts    = (unsigned*)(ws + OFF_CNT);
    unsigned* state     = (unsigned*)(ws + OFF_STATE);
    unsigned* histA     = (unsigned*)(ws + OFF_HA);
    unsigned* histB     = (unsigned*)(ws + OFF_HB);
    unsigned* bcnt      = (unsigned*)(ws + OFF_BCNT);
    unsigned* fcnt      = (unsigned*)(ws + OFF_FCNT);
    unsigned* bucket    = (unsigned*)(ws + OFF_SELB);
    float2*   fixb      = (float2*)(ws + OFF_FIXB);

    k_zero<<<(ZERO_U4 + 255) / 256, 256, 0, stream>>>((uint4*)(ws + OFF_CNT));
    k_geo<<<GEO_NBLK, 256, 0, stream>>>(ypc, ytc, ytg, ypg, tmk,
                                        counts, histA, histB, geo_part);
    k_scan1<<<B_IMG, 64, 0, stream>>>(counts, histA, histB, state);
    k_collect2<<<NBLK2, TPB, 0, stream>>>(ypc, ytc, tmk, state,
                                          bcnt, bucket, fcnt, fixb, dice_part);
    k_select<<<B_IMG, 64, 0, stream>>>(state, bcnt, bucket);
    k_fix<<<B_IMG, 256, 0, stream>>>(state, fcnt, fixb, dice_part);
    k_out<<<1, 256, 0, stream>>>(geo_part, dice_part, (float*)d_out);
}

// Round 14
// 107.499 us; speedup vs baseline: 1.1486x; 1.0030x over previous
//
#include <hip/hip_runtime.h>
#include <math.h>

#define B_IMG 16
#define HW 409600
#define HW4 102400           // HW/4
#define HW2 204800           // HW/2

// ---- k_geo geometry: 100 blocks/img, 1024 float4/block, 4 stages ----------
#define GEO_PBI 100
#define GEO_NBLK (B_IMG * GEO_PBI)   // 1600

// ---- collect geometry: 100 blocks/img, 1024 f4/block, no guards -----------
#define P_BLK 100
#define TPB 256
#define NBLK2 (B_IMG * P_BLK)        // 1600
#define DICE_SLOTS (NBLK2 + B_IMG)   // 1616

#define SEL_CAP 65536
#define FIX_CAP 65536

// workspace layout (bytes)
#define OFF_GEO    0                 // 1600 doubles (12800)
#define OFF_DICE   12800             // 1616*3 doubles (38784) -> 51584
#define OFF_CNT    51584             // 16*2 u32
#define OFF_STATE  51712             // 16*8 u32
#define OFF_HA     52224             // 16*2048 u32 (131072)
#define OFF_HB     183296            // 16*2048 u32 (131072)
#define OFF_BCNT   314368            // 16 u32
#define OFF_FCNT   314432            // 16 u32
#define ZERO_BYTES (314496 - OFF_CNT)   // 262912
#define ZERO_U4    (ZERO_BYTES / 16)    // 16432
#define OFF_SELB   314496            // 16*65536 u32 (4 MB)
#define OFF_FIXB   4508800           // 16*65536 float2 (8 MB)

union F4 { float4 v; float f[4]; };

__device__ __forceinline__ unsigned fkey(float x) {
    unsigned b = __float_as_uint(x);
    return b ^ ((b & 0x80000000u) ? 0xFFFFFFFFu : 0x80000000u);
}
__device__ __forceinline__ float funkey(unsigned k) {
    unsigned b = (k & 0x80000000u) ? (k ^ 0x80000000u) : ~k;
    return __uint_as_float(b);
}

__device__ __forceinline__ double wredd(double v) {
#pragma unroll
    for (int off = 32; off > 0; off >>= 1) v += __shfl_down(v, off);
    return v;
}
__device__ __forceinline__ unsigned wredu(unsigned v) {
#pragma unroll
    for (int off = 32; off > 0; off >>= 1) v += __shfl_down(v, off);
    return v;
}

// n-th largest: find bin and 1-based rank r within that bin. one wave.
__device__ void radix_scan(const unsigned* h, int NB, unsigned n,
                           unsigned& bin_out, unsigned& r_out, bool& tgt) {
    const int lane = threadIdx.x;
    const int seg = NB >> 6;
    const int base = lane * seg;
    unsigned segsum = 0;
    for (int j = 0; j < seg; ++j) segsum += h[base + j];
    unsigned suf = segsum;
#pragma unroll
    for (int off = 1; off < 64; off <<= 1) {
        unsigned v = __shfl_down(suf, off);
        if (lane + off < 64) suf += v;
    }
    unsigned above = suf - segsum;
    tgt = (suf >= n) && (above < n);
    bin_out = 0; r_out = 0;
    if (tgt) {
        unsigned cum = above;
        for (int j = base + seg - 1; j >= base; --j) {
            unsigned cb = cum;
            cum += h[j];
            if (cum >= n) { bin_out = (unsigned)j; r_out = n - cb; break; }
        }
    }
}

// ---------- K0: zero counts/state/hists/bucket-counters ---------------------
__global__ void __launch_bounds__(256)
k_zero(uint4* __restrict__ z) {
    const int i = blockIdx.x * 256 + threadIdx.x;
    if (i < ZERO_U4) z[i] = make_uint4(0u, 0u, 0u, 0u);
}

// ---------- K1: geo loss + counts + packed pass-1 hist, f4 1-deep -----------
struct GeoF4 {
    F4 s, g, m, d1g, d2g, d3g, d4g, thg, d1p, d2p, d3p, d4p, thp;
};

__device__ __forceinline__ void geo_load(GeoF4& r, int idx,
        const float* __restrict__ ypc, const float* __restrict__ ytc,
        const float* __restrict__ tmk, const float* __restrict__ ytg,
        const float* __restrict__ ypg, int cb, int gb) {
    r.s.v   = ((const float4*)ypc)[cb + idx];
    r.g.v   = ((const float4*)ytc)[cb + idx];
    r.m.v   = ((const float4*)tmk)[cb + idx];
    r.d1g.v = ((const float4*)ytg)[gb + 0 * HW4 + idx];
    r.d2g.v = ((const float4*)ytg)[gb + 1 * HW4 + idx];
    r.d3g.v = ((const float4*)ytg)[gb + 2 * HW4 + idx];
    r.d4g.v = ((const float4*)ytg)[gb + 3 * HW4 + idx];
    r.thg.v = ((const float4*)ytg)[gb + 4 * HW4 + idx];
    r.d1p.v = ((const float4*)ypg)[gb + 0 * HW4 + idx];
    r.d2p.v = ((const float4*)ypg)[gb + 1 * HW4 + idx];
    r.d3p.v = ((const float4*)ypg)[gb + 2 * HW4 + idx];
    r.d4p.v = ((const float4*)ypg)[gb + 3 * HW4 + idx];
    r.thp.v = ((const float4*)ypg)[gb + 4 * HW4 + idx];
}

__device__ __forceinline__ void geo_compute(const GeoF4& r, float& geo_f,
                                            unsigned& pos, unsigned& neg,
                                            unsigned long long* h) {
#pragma unroll
    for (int j = 0; j < 4; ++j) {
        const float gv = r.g.f[j], mv = r.m.f[j];
        pos += (gv > 0.5f && mv > 0.5f) ? 1u : 0u;
        const bool isneg = (gv < 0.5f);
        neg += isneg ? 1u : 0u;
        const unsigned bin = fkey(r.s.f[j]) >> 21;
        atomicAdd(&h[bin], 1ull + ((unsigned long long)(isneg ? 1u : 0u) << 32));
        const float ag = (r.d1g.f[j] + r.d3g.f[j]) * (r.d2g.f[j] + r.d4g.f[j]);
        const float ap = (r.d1p.f[j] + r.d3p.f[j]) * (r.d2p.f[j] + r.d4p.f[j]);
        const float wu = fminf(r.d2g.f[j], r.d2p.f[j]) + fminf(r.d4g.f[j], r.d4p.f[j]);
        const float hu = fminf(r.d1g.f[j], r.d1p.f[j]) + fminf(r.d3g.f[j], r.d3p.f[j]);
        const float ai = wu * hu;
        const float au = ag + ap - ai;
        const float la = __logf(__fdividef(au + 1.0f, ai + 1.0f));
        const float lt = 1.0f - __cosf(r.thp.f[j] - r.thg.f[j]);
        geo_f += (la + 20.0f * lt) * gv * mv;
    }
}

__global__ void __launch_bounds__(256)
k_geo(const float* __restrict__ ypc, const float* __restrict__ ytc,
      const float* __restrict__ ytg, const float* __restrict__ ypg,
      const float* __restrict__ tmk,
      unsigned* __restrict__ counts, unsigned* __restrict__ histA,
      unsigned* __restrict__ histB, double* __restrict__ geo_part) {
    __shared__ unsigned long long lh[2048];
    const int tid = threadIdx.x;
    const int img = blockIdx.x / GEO_PBI, blkin = blockIdx.x % GEO_PBI;
    const int cb = img * HW4;
    const int gb = img * 5 * HW4;
    const int base = blkin * 1024 + tid;

    for (int j = tid; j < 2048; j += 256) lh[j] = 0ull;
    __syncthreads();

    float geo_f = 0.0f;
    unsigned pos = 0, neg = 0;

    GeoF4 A;
    geo_load(A, base + 0 * 256, ypc, ytc, tmk, ytg, ypg, cb, gb);
    __builtin_amdgcn_sched_barrier(0);
    geo_compute(A, geo_f, pos, neg, lh);
    __builtin_amdgcn_sched_barrier(0);
    geo_load(A, base + 1 * 256, ypc, ytc, tmk, ytg, ypg, cb, gb);
    __builtin_amdgcn_sched_barrier(0);
    geo_compute(A, geo_f, pos, neg, lh);
    __builtin_amdgcn_sched_barrier(0);
    geo_load(A, base + 2 * 256, ypc, ytc, tmk, ytg, ypg, cb, gb);
    __builtin_amdgcn_sched_barrier(0);
    geo_compute(A, geo_f, pos, neg, lh);
    __builtin_amdgcn_sched_barrier(0);
    geo_load(A, base + 3 * 256, ypc, ytc, tmk, ytg, ypg, cb, gb);
    __builtin_amdgcn_sched_barrier(0);
    geo_compute(A, geo_f, pos, neg, lh);

    const double gw = wredd((double)geo_f);
    const unsigned pw = wredu(pos), nw = wredu(neg);
    __shared__ double gred[4];
    __shared__ unsigned pr[4], nr[4];
    const int lane = tid & 63, w = tid >> 6;
    if (lane == 0) { gred[w] = gw; pr[w] = pw; nr[w] = nw; }
    __syncthreads();
    if (tid == 0) {
        geo_part[blockIdx.x] = gred[0] + gred[1] + gred[2] + gred[3];
        atomicAdd(&counts[img * 2 + 0], pr[0] + pr[1] + pr[2] + pr[3]);
        atomicAdd(&counts[img * 2 + 1], nr[0] + nr[1] + nr[2] + nr[3]);
    }
    for (int j = tid; j < 2048; j += 256) {
        const unsigned long long v = lh[j];
        const unsigned a = (unsigned)(v & 0xFFFFFFFFull);
        const unsigned b = (unsigned)(v >> 32);
        if (a) atomicAdd(&histA[img * 2048 + j], a);
        if (b) atomicAdd(&histB[img * 2048 + j], b);
    }
}

// ---------- scan1: decide branch, pick 11-bit bin + rank --------------------
__global__ void k_scan1(const unsigned* __restrict__ counts,
                        const unsigned* __restrict__ histA,
                        const unsigned* __restrict__ histB,
                        unsigned* __restrict__ state) {
    const int img = blockIdx.x, lane = threadIdx.x;
    const unsigned pos = counts[img * 2 + 0], neg = counts[img * 2 + 1];
    unsigned branch, n = 1;
    if (pos == 0) {
        branch = 0;
        n = neg / 2; if (n < 1) n = 1;
    } else {
        const unsigned n3 = min(pos * 3u, neg);
        if (n3 == 0) branch = 1;
        else { branch = 2; n = n3; }
    }
    if (lane == 0) state[img * 8 + 0] = branch;
    if (branch == 1) return;
    __shared__ unsigned h[2048];
    const unsigned* g = (branch == 0 ? histA : histB) + img * 2048;
    for (int j = lane; j < 2048; j += 64) h[j] = g[j];
    __syncthreads();
    unsigned bin, r; bool tgt;
    radix_scan(h, 2048, n, bin, r, tgt);
    if (tgt) { state[img * 8 + 1] = bin; state[img * 8 + 2] = r; }
}

// ---------- collect2: in-bin keys + dice for definite pixels ----------------
__global__ void __launch_bounds__(TPB)
k_collect2(const float* __restrict__ ypc, const float* __restrict__ ytc,
           const float* __restrict__ tmk, const unsigned* __restrict__ state,
           unsigned* __restrict__ bcnt, unsigned* __restrict__ bucket,
           unsigned* __restrict__ fcnt, float2* __restrict__ fixb,
           double* __restrict__ dice_part) {
    const int img = blockIdx.x / P_BLK, blk = blockIdx.x % P_BLK;
    const unsigned branch = state[img * 8 + 0];
    const unsigned bin = state[img * 8 + 1];
    const int cbase = img * HW4 + blk * 1024;
    const int lane = threadIdx.x & 63;
    const unsigned long long lmlt = (1ull << lane) - 1ull;
    const float4* sc = (const float4*)ypc;
    const float4* gt = (const float4*)ytc;
    const float4* tm = (const float4*)tmk;
    unsigned* bk = bucket + (size_t)img * SEL_CAP;
    float2*   fb = fixb + (size_t)img * FIX_CAP;

    float di = 0.0f, dg = 0.0f, dp = 0.0f;
#pragma unroll
    for (int k = 0; k < 4; ++k) {
        const int t = threadIdx.x + k * TPB;
        F4 s, g, m; s.v = sc[cbase + t]; g.v = gt[cbase + t]; m.v = tm[cbase + t];
        if (branch == 1) {
#pragma unroll
            for (int j = 0; j < 4; ++j) {
                const float sv = s.f[j], gv = g.f[j], mv = m.f[j];
                di += gv * sv * mv; dg += gv * mv; dp += sv * mv;
            }
        } else {
#pragma unroll
            for (int j = 0; j < 4; ++j) {
                const float sv = s.f[j], gv = g.f[j], mv = m.f[j];
                const unsigned key = fkey(sv);
                const unsigned kb = key >> 21;
                const bool cand = (branch == 0) || (gv < 0.5f);
                const bool selp = cand && (kb == bin);
                const unsigned long long msk = __ballot(selp);
                if (msk) {
                    const int leader = __ffsll((long long)msk) - 1;
                    unsigned b0 = 0;
                    if (lane == leader)
                        b0 = atomicAdd(&bcnt[img], (unsigned)__popcll(msk));
                    b0 = (unsigned)__shfl((int)b0, leader);
                    const unsigned idx = b0 + (unsigned)__popcll(msk & lmlt);
                    if (selp && idx < SEL_CAP) bk[idx] = key;
                }
                bool unc; float mm;
                if (branch == 0) {
                    unc = (kb == bin);
                    mm = (kb > bin) ? 1.0f : 0.0f;
                } else {
                    if (gv > 0.5f)       { unc = false; mm = (mv > 0.5f) ? 1.0f : 0.0f; }
                    else if (mv <= 0.5f) { unc = false; mm = 0.0f; }
                    else                 { unc = (kb == bin); mm = (kb > bin) ? 1.0f : 0.0f; }
                }
                if (!unc) { di += gv * sv * mm; dg += gv * mm; dp += sv * mm; }
                const unsigned long long msk2 = __ballot(unc);
                if (msk2) {
                    const int leader = __ffsll((long long)msk2) - 1;
                    unsigned b0 = 0;
                    if (lane == leader)
                        b0 = atomicAdd(&fcnt[img], (unsigned)__popcll(msk2));
                    b0 = (unsigned)__shfl((int)b0, leader);
                    const unsigned idx = b0 + (unsigned)__popcll(msk2 & lmlt);
                    if (unc && idx < FIX_CAP) fb[idx] = make_float2(sv, gv);
                }
            }
        }
    }
    const double a = wredd((double)di), b = wredd((double)dg), c = wredd((double)dp);
    __shared__ double r[4][3];
    const int wid = threadIdx.x >> 6;
    if (lane == 0) { r[wid][0] = a; r[wid][1] = b; r[wid][2] = c; }
    __syncthreads();
    if (threadIdx.x == 0) {
        dice_part[blockIdx.x * 3 + 0] = r[0][0] + r[1][0] + r[2][0] + r[3][0];
        dice_part[blockIdx.x * 3 + 1] = r[0][1] + r[1][1] + r[2][1] + r[3][1];
        dice_part[blockIdx.x * 3 + 2] = r[0][2] + r[1][2] + r[2][2] + r[3][2];
    }
}

// ---------- select: exact n-th value within the bucket ----------------------
__global__ void k_select(unsigned* __restrict__ state,
                         const unsigned* __restrict__ bcnt,
                         const unsigned* __restrict__ bucket) {
    const int img = blockIdx.x, lane = threadIdx.x;
    const unsigned branch = state[img * 8 + 0];
    if (branch == 1) return;
    const unsigned bin = state[img * 8 + 1];
    const unsigned r = state[img * 8 + 2];
    const unsigned cnt = min(bcnt[img], (unsigned)SEL_CAP);
    const unsigned* bk = bucket + (size_t)img * SEL_CAP;
    __shared__ unsigned h[2048];
    __shared__ unsigned sh_mid, sh_r2;
    for (int j = lane; j < 2048; j += 64) h[j] = 0;
    __syncthreads();
    for (unsigned i = lane; i < cnt; i += 64)
        atomicAdd(&h[(bk[i] >> 10) & 2047u], 1u);
    __syncthreads();
    unsigned mid, r2; bool tgt;
    radix_scan(h, 2048, r, mid, r2, tgt);
    if (tgt) { sh_mid = mid; sh_r2 = r2; }
    __syncthreads();
    mid = sh_mid; r2 = sh_r2;
    for (int j = lane; j < 1024; j += 64) h[j] = 0;
    __syncthreads();
    for (unsigned i = lane; i < cnt; i += 64) {
        const unsigned k = bk[i];
        if (((k >> 10) & 2047u) == mid) atomicAdd(&h[k & 1023u], 1u);
    }
    __syncthreads();
    unsigned low, r3;
    radix_scan(h, 1024, r2, low, r3, tgt);
    if (tgt)
        state[img * 8 + 4] = __float_as_uint(funkey((bin << 21) | (mid << 10) | low));
}

// ---------- fix: dice contribution of the in-bin pixels ---------------------
__global__ void __launch_bounds__(256)
k_fix(const unsigned* __restrict__ state, const unsigned* __restrict__ fcnt,
      const float2* __restrict__ fixb, double* __restrict__ dice_part) {
    const int img = blockIdx.x;
    const unsigned branch = state[img * 8 + 0];
    const float thr = __uint_as_float(state[img * 8 + 4]);
    double di = 0.0, dg = 0.0, dp = 0.0;
    if (branch != 1) {
        const unsigned cnt = min(fcnt[img], (unsigned)FIX_CAP);
        const float2* fb = fixb + (size_t)img * FIX_CAP;
        for (unsigned i = threadIdx.x; i < cnt; i += 256) {
            const float sv = fb[i].x, gv = fb[i].y;
            if (sv >= thr) { di += (double)(gv * sv); dg += (double)gv; dp += (double)sv; }
        }
    }
    const double a = wredd(di), b = wredd(dg), c = wredd(dp);
    __shared__ double r[4][3];
    const int lane = threadIdx.x & 63, wid = threadIdx.x >> 6;
    if (lane == 0) { r[wid][0] = a; r[wid][1] = b; r[wid][2] = c; }
    __syncthreads();
    if (threadIdx.x == 0) {
        const int slot = NBLK2 + img;
        dice_part[slot * 3 + 0] = r[0][0] + r[1][0] + r[2][0] + r[3][0];
        dice_part[slot * 3 + 1] = r[0][1] + r[1][1] + r[2][1] + r[3][1];
        dice_part[slot * 3 + 2] = r[0][2] + r[1][2] + r[2][2] + r[3][2];
    }
}

// ---------- combine ---------------------------------------------------------
__global__ void __launch_bounds__(256)
k_out(const double* __restrict__ geo_part, const double* __restrict__ dice_part,
      float* __restrict__ out) {
    double geo = 0.0, di = 0.0, dg = 0.0, dp = 0.0;
    for (int i = threadIdx.x; i < DICE_SLOTS; i += 256) {
        if (i < GEO_NBLK) geo += geo_part[i];
        di += dice_part[i * 3 + 0];
        dg += dice_part[i * 3 + 1];
        dp += dice_part[i * 3 + 2];
    }
    geo = wredd(geo); di = wredd(di); dg = wredd(dg); dp = wredd(dp);
    __shared__ double r[4][4];
    const int lane = threadIdx.x & 63, wid = threadIdx.x >> 6;
    if (lane == 0) { r[wid][0] = geo; r[wid][1] = di; r[wid][2] = dg; r[wid][3] = dp; }
    __syncthreads();
    if (threadIdx.x == 0) {
        geo = r[0][0] + r[1][0] + r[2][0] + r[3][0];
        di  = r[0][1] + r[1][1] + r[2][1] + r[3][1];
        dg  = r[0][2] + r[1][2] + r[2][2] + r[3][2];
        dp  = r[0][3] + r[1][3] + r[2][3] + r[3][3];
        const double mean = geo / (double)((double)B_IMG * (double)HW);
        const double uni = dg + dp + 1e-05;
        const double loss = mean + 0.01 * (1.0 - 2.0 * di / uni);
        out[0] = (float)loss;
    }
}

extern "C" void kernel_launch(void* const* d_in, const int* in_sizes, int n_in,
                              void* d_out, int out_size, void* d_ws, size_t ws_size,
                              hipStream_t stream) {
    const float* ytc = (const float*)d_in[0];  // y_true_cls  (gt)
    const float* ypc = (const float*)d_in[1];  // y_pred_cls  (score)
    const float* ytg = (const float*)d_in[2];  // y_true_geo
    const float* ypg = (const float*)d_in[3];  // y_pred_geo
    const float* tmk = (const float*)d_in[4];  // training_mask

    char* ws = (char*)d_ws;
    double*   geo_part  = (double*)(ws + OFF_GEO);
    double*   dice_part = (double*)(ws + OFF_DICE);
    unsigned* counts    = (unsigned*)(ws + OFF_CNT);
    unsigned* state     = (unsigned*)(ws + OFF_STATE);
    unsigned* histA     = (unsigned*)(ws + OFF_HA);
    unsigned* histB     = (unsigned*)(ws + OFF_HB);
    unsigned* bcnt      = (unsigned*)(ws + OFF_BCNT);
    unsigned* fcnt      = (unsigned*)(ws + OFF_FCNT);
    unsigned* bucket    = (unsigned*)(ws + OFF_SELB);
    float2*   fixb      = (float2*)(ws + OFF_FIXB);

    k_zero<<<(ZERO_U4 + 255) / 256, 256, 0, stream>>>((uint4*)(ws + OFF_CNT));
    k_geo<<<GEO_NBLK, 256, 0, stream>>>(ypc, ytc, ytg, ypg, tmk,
                                        counts, histA, histB, geo_part);
    k_scan1<<<B_IMG, 64, 0, stream>>>(counts, histA, histB, state);
    k_collect2<<<NBLK2, TPB, 0, stream>>>(ypc, ytc, tmk, state,
                                          bcnt, bucket, fcnt, fixb, dice_part);
    k_select<<<B_IMG, 64, 0, stream>>>(state, bcnt, bucket);
    k_fix<<<B_IMG, 256, 0, stream>>>(state, fcnt, fixb, dice_part);
    k_out<<<1, 256, 0, stream>>>(geo_part, dice_part, (float*)d_out);
}

// Round 15
// 105.214 us; speedup vs baseline: 1.1735x; 1.0217x over previous
//
#include <hip/hip_runtime.h>
#include <math.h>

#define B_IMG 16
#define HW 409600
#define HW4 102400           // HW/4
#define HW2 204800           // HW/2

// ---- k_geo geometry: 100 blocks/img, 4096 elems/block, 8 float2 stages ----
#define GEO_PBI 100
#define GEO_NBLK (B_IMG * GEO_PBI)   // 1600

// ---- collect geometry: 100 blocks/img, 1024 f4/block, no guards -----------
#define P_BLK 100
#define TPB 256
#define NBLK2 (B_IMG * P_BLK)        // 1600
#define DICE_SLOTS (NBLK2 + B_IMG)   // 1616

#define SEL_CAP 65536
#define FIX_CAP 65536

// workspace layout (bytes)
#define OFF_GEO    0                 // 1600 doubles (12800)
#define OFF_DICE   12800             // 1616*3 doubles (38784) -> 51584
#define OFF_CNT    51584             // 16*2 u32
#define OFF_STATE  51712             // 16*8 u32
#define OFF_HA     52224             // 16*2048 u32 (131072)
#define OFF_HB     183296            // 16*2048 u32 (131072)
#define OFF_BCNT   314368            // 16 u32
#define OFF_FCNT   314432            // 16 u32
#define ZERO_BYTES (314496 - OFF_CNT)   // 262912
#define ZERO_U4    (ZERO_BYTES / 16)    // 16432
#define OFF_SELB   314496            // 16*65536 u32 (4 MB)
#define OFF_FIXB   4508800           // 16*65536 float2 (8 MB)

typedef float f32x2 __attribute__((ext_vector_type(2)));

union F4 { float4 v; float f[4]; };
union F2 { float2 v; f32x2 n; float f[2]; };

__device__ __forceinline__ f32x2 ntload2(const float* p) {
    return __builtin_nontemporal_load((const f32x2*)p);
}

__device__ __forceinline__ unsigned fkey(float x) {
    unsigned b = __float_as_uint(x);
    return b ^ ((b & 0x80000000u) ? 0xFFFFFFFFu : 0x80000000u);
}
__device__ __forceinline__ float funkey(unsigned k) {
    unsigned b = (k & 0x80000000u) ? (k ^ 0x80000000u) : ~k;
    return __uint_as_float(b);
}

__device__ __forceinline__ double wredd(double v) {
#pragma unroll
    for (int off = 32; off > 0; off >>= 1) v += __shfl_down(v, off);
    return v;
}
__device__ __forceinline__ unsigned wredu(unsigned v) {
#pragma unroll
    for (int off = 32; off > 0; off >>= 1) v += __shfl_down(v, off);
    return v;
}

// n-th largest: find bin and 1-based rank r within that bin. one wave.
__device__ void radix_scan(const unsigned* h, int NB, unsigned n,
                           unsigned& bin_out, unsigned& r_out, bool& tgt) {
    const int lane = threadIdx.x;
    const int seg = NB >> 6;
    const int base = lane * seg;
    unsigned segsum = 0;
    for (int j = 0; j < seg; ++j) segsum += h[base + j];
    unsigned suf = segsum;
#pragma unroll
    for (int off = 1; off < 64; off <<= 1) {
        unsigned v = __shfl_down(suf, off);
        if (lane + off < 64) suf += v;
    }
    unsigned above = suf - segsum;
    tgt = (suf >= n) && (above < n);
    bin_out = 0; r_out = 0;
    if (tgt) {
        unsigned cum = above;
        for (int j = base + seg - 1; j >= base; --j) {
            unsigned cb = cum;
            cum += h[j];
            if (cum >= n) { bin_out = (unsigned)j; r_out = n - cb; break; }
        }
    }
}

// ---------- K0: zero counts/state/hists/bucket-counters ---------------------
__global__ void __launch_bounds__(256)
k_zero(uint4* __restrict__ z) {
    const int i = blockIdx.x * 256 + threadIdx.x;
    if (i < ZERO_U4) z[i] = make_uint4(0u, 0u, 0u, 0u);
}

// ---------- K1: geo loss + counts + packed pass-1 hist (fused) --------------
struct Geo13 {
    F2 s, g, m, d1g, d2g, d3g, d4g, thg, d1p, d2p, d3p, d4p, thp;
};

__device__ __forceinline__ void geo_load(Geo13& r, int idx,
        const float* __restrict__ ypc, const float* __restrict__ ytc,
        const float* __restrict__ tmk, const float* __restrict__ ytg,
        const float* __restrict__ ypg, int cb, int gb) {
    r.s.v   = ((const float2*)ypc)[cb + idx];
    r.g.v   = ((const float2*)ytc)[cb + idx];
    r.m.v   = ((const float2*)tmk)[cb + idx];
    r.d1g.n = ntload2(ytg + 2 * (gb + 0 * HW2 + idx));
    r.d2g.n = ntload2(ytg + 2 * (gb + 1 * HW2 + idx));
    r.d3g.n = ntload2(ytg + 2 * (gb + 2 * HW2 + idx));
    r.d4g.n = ntload2(ytg + 2 * (gb + 3 * HW2 + idx));
    r.thg.n = ntload2(ytg + 2 * (gb + 4 * HW2 + idx));
    r.d1p.n = ntload2(ypg + 2 * (gb + 0 * HW2 + idx));
    r.d2p.n = ntload2(ypg + 2 * (gb + 1 * HW2 + idx));
    r.d3p.n = ntload2(ypg + 2 * (gb + 2 * HW2 + idx));
    r.d4p.n = ntload2(ypg + 2 * (gb + 3 * HW2 + idx));
    r.thp.n = ntload2(ypg + 2 * (gb + 4 * HW2 + idx));
}

__device__ __forceinline__ void geo_compute(const Geo13& r, float& geo_f,
                                            unsigned& pos, unsigned& neg,
                                            unsigned long long* h) {
#pragma unroll
    for (int j = 0; j < 2; ++j) {
        const float gv = r.g.f[j], mv = r.m.f[j];
        pos += (gv > 0.5f && mv > 0.5f) ? 1u : 0u;
        const bool isneg = (gv < 0.5f);
        neg += isneg ? 1u : 0u;
        const unsigned bin = fkey(r.s.f[j]) >> 21;
        atomicAdd(&h[bin], 1ull + ((unsigned long long)(isneg ? 1u : 0u) << 32));
        const float ag = (r.d1g.f[j] + r.d3g.f[j]) * (r.d2g.f[j] + r.d4g.f[j]);
        const float ap = (r.d1p.f[j] + r.d3p.f[j]) * (r.d2p.f[j] + r.d4p.f[j]);
        const float wu = fminf(r.d2g.f[j], r.d2p.f[j]) + fminf(r.d4g.f[j], r.d4p.f[j]);
        const float hu = fminf(r.d1g.f[j], r.d1p.f[j]) + fminf(r.d3g.f[j], r.d3p.f[j]);
        const float ai = wu * hu;
        const float au = ag + ap - ai;
        const float la = __logf(__fdividef(au + 1.0f, ai + 1.0f));
        const float lt = 1.0f - __cosf(r.thp.f[j] - r.thg.f[j]);
        geo_f += (la + 20.0f * lt) * gv * mv;
    }
}

__global__ void __launch_bounds__(256)
k_geo(const float* __restrict__ ypc, const float* __restrict__ ytc,
      const float* __restrict__ ytg, const float* __restrict__ ypg,
      const float* __restrict__ tmk,
      unsigned* __restrict__ counts, unsigned* __restrict__ histA,
      unsigned* __restrict__ histB, double* __restrict__ geo_part) {
    __shared__ unsigned long long lh[2048];
    const int tid = threadIdx.x;
    const int img = blockIdx.x / GEO_PBI, blkin = blockIdx.x % GEO_PBI;
    const int cb = img * HW2;
    const int gb = img * 5 * HW2;
    const int base = blkin * 2048 + tid;

    for (int j = tid; j < 2048; j += 256) lh[j] = 0ull;
    __syncthreads();

    float geo_f = 0.0f;
    unsigned pos = 0, neg = 0;

    Geo13 A, B;
    geo_load(A, base + 0 * 256, ypc, ytc, tmk, ytg, ypg, cb, gb);
    geo_load(B, base + 1 * 256, ypc, ytc, tmk, ytg, ypg, cb, gb);
    __builtin_amdgcn_sched_barrier(0);
    geo_compute(A, geo_f, pos, neg, lh);
    geo_load(A, base + 2 * 256, ypc, ytc, tmk, ytg, ypg, cb, gb);
    __builtin_amdgcn_sched_barrier(0);
    geo_compute(B, geo_f, pos, neg, lh);
    geo_load(B, base + 3 * 256, ypc, ytc, tmk, ytg, ypg, cb, gb);
    __builtin_amdgcn_sched_barrier(0);
    geo_compute(A, geo_f, pos, neg, lh);
    geo_load(A, base + 4 * 256, ypc, ytc, tmk, ytg, ypg, cb, gb);
    __builtin_amdgcn_sched_barrier(0);
    geo_compute(B, geo_f, pos, neg, lh);
    geo_load(B, base + 5 * 256, ypc, ytc, tmk, ytg, ypg, cb, gb);
    __builtin_amdgcn_sched_barrier(0);
    geo_compute(A, geo_f, pos, neg, lh);
    geo_load(A, base + 6 * 256, ypc, ytc, tmk, ytg, ypg, cb, gb);
    __builtin_amdgcn_sched_barrier(0);
    geo_compute(B, geo_f, pos, neg, lh);
    geo_load(B, base + 7 * 256, ypc, ytc, tmk, ytg, ypg, cb, gb);
    __builtin_amdgcn_sched_barrier(0);
    geo_compute(A, geo_f, pos, neg, lh);
    geo_compute(B, geo_f, pos, neg, lh);

    const double gw = wredd((double)geo_f);
    const unsigned pw = wredu(pos), nw = wredu(neg);
    __shared__ double gred[4];
    __shared__ unsigned pr[4], nr[4];
    const int lane = tid & 63, w = tid >> 6;
    if (lane == 0) { gred[w] = gw; pr[w] = pw; nr[w] = nw; }
    __syncthreads();
    if (tid == 0) {
        geo_part[blockIdx.x] = gred[0] + gred[1] + gred[2] + gred[3];
        atomicAdd(&counts[img * 2 + 0], pr[0] + pr[1] + pr[2] + pr[3]);
        atomicAdd(&counts[img * 2 + 1], nr[0] + nr[1] + nr[2] + nr[3]);
    }
    for (int j = tid; j < 2048; j += 256) {
        const unsigned long long v = lh[j];
        const unsigned a = (unsigned)(v & 0xFFFFFFFFull);
        const unsigned b = (unsigned)(v >> 32);
        if (a) atomicAdd(&histA[img * 2048 + j], a);
        if (b) atomicAdd(&histB[img * 2048 + j], b);
    }
}

// ---------- scan1: decide branch, pick 11-bit bin + rank --------------------
__global__ void k_scan1(const unsigned* __restrict__ counts,
                        const unsigned* __restrict__ histA,
                        const unsigned* __restrict__ histB,
                        unsigned* __restrict__ state) {
    const int img = blockIdx.x, lane = threadIdx.x;
    const unsigned pos = counts[img * 2 + 0], neg = counts[img * 2 + 1];
    unsigned branch, n = 1;
    if (pos == 0) {
        branch = 0;
        n = neg / 2; if (n < 1) n = 1;
    } else {
        const unsigned n3 = min(pos * 3u, neg);
        if (n3 == 0) branch = 1;
        else { branch = 2; n = n3; }
    }
    if (lane == 0) state[img * 8 + 0] = branch;
    if (branch == 1) return;
    __shared__ unsigned h[2048];
    const unsigned* g = (branch == 0 ? histA : histB) + img * 2048;
    for (int j = lane; j < 2048; j += 64) h[j] = g[j];
    __syncthreads();
    unsigned bin, r; bool tgt;
    radix_scan(h, 2048, n, bin, r, tgt);
    if (tgt) { state[img * 8 + 1] = bin; state[img * 8 + 2] = r; }
}

// ---------- collect2: in-bin keys + dice for definite pixels ----------------
__global__ void __launch_bounds__(TPB)
k_collect2(const float* __restrict__ ypc, const float* __restrict__ ytc,
           const float* __restrict__ tmk, const unsigned* __restrict__ state,
           unsigned* __restrict__ bcnt, unsigned* __restrict__ bucket,
           unsigned* __restrict__ fcnt, float2* __restrict__ fixb,
           double* __restrict__ dice_part) {
    const int img = blockIdx.x / P_BLK, blk = blockIdx.x % P_BLK;
    const unsigned branch = state[img * 8 + 0];
    const unsigned bin = state[img * 8 + 1];
    const int cbase = img * HW4 + blk * 1024;
    const int lane = threadIdx.x & 63;
    const unsigned long long lmlt = (1ull << lane) - 1ull;
    const float4* sc = (const float4*)ypc;
    const float4* gt = (const float4*)ytc;
    const float4* tm = (const float4*)tmk;
    unsigned* bk = bucket + (size_t)img * SEL_CAP;
    float2*   fb = fixb + (size_t)img * FIX_CAP;

    float di = 0.0f, dg = 0.0f, dp = 0.0f;
#pragma unroll
    for (int k = 0; k < 4; ++k) {
        const int t = threadIdx.x + k * TPB;
        F4 s, g, m; s.v = sc[cbase + t]; g.v = gt[cbase + t]; m.v = tm[cbase + t];
        if (branch == 1) {
#pragma unroll
            for (int j = 0; j < 4; ++j) {
                const float sv = s.f[j], gv = g.f[j], mv = m.f[j];
                di += gv * sv * mv; dg += gv * mv; dp += sv * mv;
            }
        } else {
#pragma unroll
            for (int j = 0; j < 4; ++j) {
                const float sv = s.f[j], gv = g.f[j], mv = m.f[j];
                const unsigned key = fkey(sv);
                const unsigned kb = key >> 21;
                const bool cand = (branch == 0) || (gv < 0.5f);
                const bool selp = cand && (kb == bin);
                const unsigned long long msk = __ballot(selp);
                if (msk) {
                    const int leader = __ffsll((long long)msk) - 1;
                    unsigned b0 = 0;
                    if (lane == leader)
                        b0 = atomicAdd(&bcnt[img], (unsigned)__popcll(msk));
                    b0 = (unsigned)__shfl((int)b0, leader);
                    const unsigned idx = b0 + (unsigned)__popcll(msk & lmlt);
                    if (selp && idx < SEL_CAP) bk[idx] = key;
                }
                bool unc; float mm;
                if (branch == 0) {
                    unc = (kb == bin);
                    mm = (kb > bin) ? 1.0f : 0.0f;
                } else {
                    if (gv > 0.5f)       { unc = false; mm = (mv > 0.5f) ? 1.0f : 0.0f; }
                    else if (mv <= 0.5f) { unc = false; mm = 0.0f; }
                    else                 { unc = (kb == bin); mm = (kb > bin) ? 1.0f : 0.0f; }
                }
                if (!unc) { di += gv * sv * mm; dg += gv * mm; dp += sv * mm; }
                const unsigned long long msk2 = __ballot(unc);
                if (msk2) {
                    const int leader = __ffsll((long long)msk2) - 1;
                    unsigned b0 = 0;
                    if (lane == leader)
                        b0 = atomicAdd(&fcnt[img], (unsigned)__popcll(msk2));
                    b0 = (unsigned)__shfl((int)b0, leader);
                    const unsigned idx = b0 + (unsigned)__popcll(msk2 & lmlt);
                    if (unc && idx < FIX_CAP) fb[idx] = make_float2(sv, gv);
                }
            }
        }
    }
    const double a = wredd((double)di), b = wredd((double)dg), c = wredd((double)dp);
    __shared__ double r[4][3];
    const int wid = threadIdx.x >> 6;
    if (lane == 0) { r[wid][0] = a; r[wid][1] = b; r[wid][2] = c; }
    __syncthreads();
    if (threadIdx.x == 0) {
        dice_part[blockIdx.x * 3 + 0] = r[0][0] + r[1][0] + r[2][0] + r[3][0];
        dice_part[blockIdx.x * 3 + 1] = r[0][1] + r[1][1] + r[2][1] + r[3][1];
        dice_part[blockIdx.x * 3 + 2] = r[0][2] + r[1][2] + r[2][2] + r[3][2];
    }
}

// ---------- select: exact n-th value within the bucket ----------------------
__global__ void k_select(unsigned* __restrict__ state,
                         const unsigned* __restrict__ bcnt,
                         const unsigned* __restrict__ bucket) {
    const int img = blockIdx.x, lane = threadIdx.x;
    const unsigned branch = state[img * 8 + 0];
    if (branch == 1) return;
    const unsigned bin = state[img * 8 + 1];
    const unsigned r = state[img * 8 + 2];
    const unsigned cnt = min(bcnt[img], (unsigned)SEL_CAP);
    const unsigned* bk = bucket + (size_t)img * SEL_CAP;
    __shared__ unsigned h[2048];
    __shared__ unsigned sh_mid, sh_r2;
    for (int j = lane; j < 2048; j += 64) h[j] = 0;
    __syncthreads();
    for (unsigned i = lane; i < cnt; i += 64)
        atomicAdd(&h[(bk[i] >> 10) & 2047u], 1u);
    __syncthreads();
    unsigned mid, r2; bool tgt;
    radix_scan(h, 2048, r, mid, r2, tgt);
    if (tgt) { sh_mid = mid; sh_r2 = r2; }
    __syncthreads();
    mid = sh_mid; r2 = sh_r2;
    for (int j = lane; j < 1024; j += 64) h[j] = 0;
    __syncthreads();
    for (unsigned i = lane; i < cnt; i += 64) {
        const unsigned k = bk[i];
        if (((k >> 10) & 2047u) == mid) atomicAdd(&h[k & 1023u], 1u);
    }
    __syncthreads();
    unsigned low, r3;
    radix_scan(h, 1024, r2, low, r3, tgt);
    if (tgt)
        state[img * 8 + 4] = __float_as_uint(funkey((bin << 21) | (mid << 10) | low));
}

// ---------- fix: dice contribution of the in-bin pixels ---------------------
__global__ void __launch_bounds__(256)
k_fix(const unsigned* __restrict__ state, const unsigned* __restrict__ fcnt,
      const float2* __restrict__ fixb, double* __restrict__ dice_part) {
    const int img = blockIdx.x;
    const unsigned branch = state[img * 8 + 0];
    const float thr = __uint_as_float(state[img * 8 + 4]);
    double di = 0.0, dg = 0.0, dp = 0.0;
    if (branch != 1) {
        const unsigned cnt = min(fcnt[img], (unsigned)FIX_CAP);
        const float2* fb = fixb + (size_t)img * FIX_CAP;
        for (unsigned i = threadIdx.x; i < cnt; i += 256) {
            const float sv = fb[i].x, gv = fb[i].y;
            if (sv >= thr) { di += (double)(gv * sv); dg += (double)gv; dp += (double)sv; }
        }
    }
    const double a = wredd(di), b = wredd(dg), c = wredd(dp);
    __shared__ double r[4][3];
    const int lane = threadIdx.x & 63, wid = threadIdx.x >> 6;
    if (lane == 0) { r[wid][0] = a; r[wid][1] = b; r[wid][2] = c; }
    __syncthreads();
    if (threadIdx.x == 0) {
        const int slot = NBLK2 + img;
        dice_part[slot * 3 + 0] = r[0][0] + r[1][0] + r[2][0] + r[3][0];
        dice_part[slot * 3 + 1] = r[0][1] + r[1][1] + r[2][1] + r[3][1];
        dice_part[slot * 3 + 2] = r[0][2] + r[1][2] + r[2][2] + r[3][2];
    }
}

// ---------- combine ---------------------------------------------------------
__global__ void __launch_bounds__(256)
k_out(const double* __restrict__ geo_part, const double* __restrict__ dice_part,
      float* __restrict__ out) {
    double geo = 0.0, di = 0.0, dg = 0.0, dp = 0.0;
    for (int i = threadIdx.x; i < DICE_SLOTS; i += 256) {
        if (i < GEO_NBLK) geo += geo_part[i];
        di += dice_part[i * 3 + 0];
        dg += dice_part[i * 3 + 1];
        dp += dice_part[i * 3 + 2];
    }
    geo = wredd(geo); di = wredd(di); dg = wredd(dg); dp = wredd(dp);
    __shared__ double r[4][4];
    const int lane = threadIdx.x & 63, wid = threadIdx.x >> 6;
    if (lane == 0) { r[wid][0] = geo; r[wid][1] = di; r[wid][2] = dg; r[wid][3] = dp; }
    __syncthreads();
    if (threadIdx.x == 0) {
        geo = r[0][0] + r[1][0] + r[2][0] + r[3][0];
        di  = r[0][1] + r[1][1] + r[2][1] + r[3][1];
        dg  = r[0][2] + r[1][2] + r[2][2] + r[3][2];
        dp  = r[0][3] + r[1][3] + r[2][3] + r[3][3];
        const double mean = geo / (double)((double)B_IMG * (double)HW);
        const double uni = dg + dp + 1e-05;
        const double loss = mean + 0.01 * (1.0 - 2.0 * di / uni);
        out[0] = (float)loss;
    }
}

extern "C" void kernel_launch(void* const* d_in, const int* in_sizes, int n_in,
                              void* d_out, int out_size, void* d_ws, size_t ws_size,
                              hipStream_t stream) {
    const float* ytc = (const float*)d_in[0];  // y_true_cls  (gt)
    const float* ypc = (const float*)d_in[1];  // y_pred_cls  (score)
    const float* ytg = (const float*)d_in[2];  // y_true_geo
    const float* ypg = (const float*)d_in[3];  // y_pred_geo
    const float* tmk = (const float*)d_in[4];  // training_mask

    char* ws = (char*)d_ws;
    double*   geo_part  = (double*)(ws + OFF_GEO);
    double*   dice_part = (double*)(ws + OFF_DICE);
    unsigned* counts    = (unsigned*)(ws + OFF_CNT);
    unsigned* state     = (unsigned*)(ws + OFF_STATE);
    unsigned* histA     = (unsigned*)(ws + OFF_HA);
    unsigned* histB     = (unsigned*)(ws + OFF_HB);
    unsigned* bcnt      = (unsigned*)(ws + OFF_BCNT);
    unsigned* fcnt      = (unsigned*)(ws + OFF_FCNT);
    unsigned* bucket    = (unsigned*)(ws + OFF_SELB);
    float2*   fixb      = (float2*)(ws + OFF_FIXB);

    k_zero<<<(ZERO_U4 + 255) / 256, 256, 0, stream>>>((uint4*)(ws + OFF_CNT));
    k_geo<<<GEO_NBLK, 256, 0, stream>>>(ypc, ytc, ytg, ypg, tmk,
                                        counts, histA, histB, geo_part);
    k_scan1<<<B_IMG, 64, 0, stream>>>(counts, histA, histB, state);
    k_collect2<<<NBLK2, TPB, 0, stream>>>(ypc, ytc, tmk, state,
                                          bcnt, bucket, fcnt, fixb, dice_part);
    k_select<<<B_IMG, 64, 0, stream>>>(state, bcnt, bucket);
    k_fix<<<B_IMG, 256, 0, stream>>>(state, fcnt, fixb, dice_part);
    k_out<<<1, 256, 0, stream>>>(geo_part, dice_part, (float*)d_out);
}